// Round 12
// baseline (65.492 us; speedup 1.0000x reference)
//
#include <hip/hip_runtime.h>
#include <hip/hip_bf16.h>
#include <cmath>

#define SEQ   168
#define NF    8
#define PRED  24
#define HID   8
#define KTOT  1344          // SEQ*NF (x row flat length)
#define PI_F  3.14159265358979323846f

// ---------------- workspace layout ----------------
#define WS_ROTC     256      // floats: 3*2*4*4 rot coeffs
#define WS_CGIN     512      // floats: 8 gin constants
#define WS_WT       1024     // floats: 168*640 composed weights, ends 108544
#define WS_Y0       1000000  // floats: y0[16384][400]
#define WS_Y1       8000000  // floats: y1[16384][400]
#define WS_IMG_BYTE 524288   // bytes: lane-exact B image 192*1024 = 196608

typedef __attribute__((ext_vector_type(8))) short bf16x8;
typedef __attribute__((ext_vector_type(4))) float f32x4;

__device__ __forceinline__ float frcp(float x)  { return __builtin_amdgcn_rcpf(x); }
__device__ __forceinline__ float ftanh(float x) {
    float xc = fminf(fmaxf(x, -15.f), 15.f);
    float e  = __expf(2.f * xc);
    return (e - 1.f) * frcp(e + 1.f);
}
__device__ __forceinline__ float sigm(float x) { return frcp(1.f + __expf(-x)); }
__device__ __forceinline__ unsigned short f2bf(float f) {
    __hip_bfloat16 h = __float2bfloat16(f);
    return __builtin_bit_cast(unsigned short, h);
}
__device__ __forceinline__ unsigned pack2(float a, float b) {
    return (unsigned)f2bf(a) | ((unsigned)f2bf(b) << 16);
}

// ---------------- compose conv into projection weights (f32, verified r1-r11) ----------------
__global__ void k_compose(const float* __restrict__ decomp_w,
                          const float* __restrict__ trend_w,
                          const float* __restrict__ seasonal_w,
                          const float* __restrict__ ta_w,
                          float* __restrict__ Wt) {
    __shared__ float dwsh[NF * 25];
    int t = threadIdx.x;
    if (t < NF) {
        const float* row = decomp_w + t * 25;
        float m = row[0];
        for (int k = 1; k < 25; ++k) m = fmaxf(m, row[k]);
        float e[25]; float sum = 0.f;
        for (int k = 0; k < 25; ++k) { e[k] = expf(row[k] - m); sum += e[k]; }
        float inv = 1.f / sum;
        for (int k = 0; k < 25; ++k) dwsh[t * 25 + k] = e[k] * inv;
    }
    __syncthreads();
    int n = blockIdx.x * 256 + t;
    if (n >= SEQ * 640) return;
    int sx  = n / 640;
    int col = n % 640;
    int j = col >> 3;
    int f = col & 7;
    const float* dwf = dwsh + f * 25;
    const float* wsel;
    int isTrend = 0;
    if (j < 24)      { wsel = trend_w    + j        * SEQ; isTrend = 1; }
    else if (j < 48) { wsel = seasonal_w + (j - 24) * SEQ; }
    else             { wsel = ta_w       + (j - 48) * SEQ; }
    float acc = 0.f;
    if (sx == 0) {
        for (int s = 0; s <= 12; ++s) {
            float cw = 0.f;
            for (int k = 0; k <= 12 - s; ++k) cw += dwf[k];
            acc = fmaf(cw, wsel[s], acc);
        }
    } else if (sx == 167) {
        for (int s = 155; s < 168; ++s) {
            float cw = 0.f;
            for (int k = 179 - s; k < 25; ++k) cw += dwf[k];
            acc = fmaf(cw, wsel[s], acc);
        }
    } else {
        int lo = sx - 12; if (lo < 0) lo = 0;
        int hi = sx + 12; if (hi > 167) hi = 167;
        for (int s = lo; s <= hi; ++s) acc = fmaf(dwf[sx - s + 12], wsel[s], acc);
    }
    Wt[sx * 640 + col] = isTrend ? acc : (wsel[sx] - acc);
}

// ---------------- lane-exact B image + rotc/cgin (verified r10) ----------------
__global__ void k_img(const float* __restrict__ Wt, const float* __restrict__ sc_w,
                      const float* __restrict__ h0_w,
                      const float* __restrict__ vr, const float* __restrict__ vu,
                      const float* __restrict__ vc,
                      const float* __restrict__ sc_b, const float* __restrict__ ta_b,
                      float* __restrict__ rotc, float* __restrict__ cgin,
                      unsigned char* __restrict__ imgb) {
    int idx = blockIdx.x * 256 + threadIdx.x;
    if (idx < 12288) {
        int lane = idx & 63;
        int rest = idx >> 6;          // (f*4+cf)*6+ks
        int ks = rest % 6;
        int fc = rest / 6;
        int cf = fc & 3, f = fc >> 2;
        int lr = lane & 15, lg = lane >> 4;
        unsigned short vals[8];
        #pragma unroll
        for (int e = 0; e < 8; ++e) {
            int k = ks * 32 + lg * 8 + e;           // = s
            float val = 0.f;
            if (k < SEQ) {
                if (cf < 3) {
                    int c = cf * 16 + lr;
                    int ts = (c >= 24);
                    int p  = ts ? (c - 24) : c;
                    val = Wt[k * 640 + ts * 192 + p * 8 + f];
                } else if (lr < 8) {
                    float a = 0.f;
                    for (int cc = 0; cc < 32; ++cc)
                        a = fmaf(sc_w[lr * 256 + f * 32 + cc], Wt[k * 640 + 384 + cc * 8 + f], a);
                    val = a;
                } else if (f == 7) {
                    const int LIDX[11] = {167,166,165,164,163,162,145,144,143,1,0};
                    #pragma unroll
                    for (int i = 0; i < 11; ++i)
                        if (k == LIDX[i]) val = h0_w[(lr - 8) * 11 + i];
                }
            }
            vals[e] = f2bf(val);
        }
        uint4 o;
        o.x = (unsigned)vals[0] | ((unsigned)vals[1] << 16);
        o.y = (unsigned)vals[2] | ((unsigned)vals[3] << 16);
        o.z = (unsigned)vals[4] | ((unsigned)vals[5] << 16);
        o.w = (unsigned)vals[6] | ((unsigned)vals[7] << 16);
        *(uint4*)(imgb + (size_t)rest * 1024 + lane * 16) = o;
    } else if (blockIdx.x == 48) {
        int t = threadIdx.x;
        if (t >= 64 && t < 88) {
            int n = t - 64;
            int v = n / 8, rest = n % 8;
            const float* w = (v == 0 ? vr : (v == 1 ? vu : vc)) + rest * 3;
            float phi = w[0], th = w[1], om = w[2];
            float c = cosf(0.5f * th), s = sinf(0.5f * th);
            float ap = -0.5f * (phi + om);
            float am =  0.5f * (phi - om);
            float* o = rotc + n * 4;
            o[0] = cosf(ap) * c;
            o[1] = sinf(ap) * c;
            o[2] = cosf(am) * s;
            o[3] = sinf(am) * s;
        } else if (t >= 96 && t < 104) {
            int h = t - 96;
            float a = sc_b[h];
            for (int cc = 0; cc < 32; ++cc) {
                float s = 0.f;
                for (int f = 0; f < 8; ++f) s += sc_w[h * 256 + f * 32 + cc];
                a = fmaf(ta_b[cc], s, a);
            }
            cgin[h] = a;
        }
    }
}

// ---------------- k_gemm: SPLIT-K=2, slim block (3 blocks/CU target) ----------------
// grid (512, 2): blockIdx.y = K-half (3 chunks each). M=32, 8 waves, wave w = feature f=w.
// LDS 32KB (A dbuf 2x16KB; ghpart overlays buf1 after last MFMA reads buf0).
__global__ __launch_bounds__(512, 3)
void k_gemm(const float* __restrict__ x, const unsigned char* __restrict__ img,
            float* __restrict__ y0, float* __restrict__ y1, int Btot)
{
    __shared__ unsigned char lds[32768];           // A dbuf [2][8 f][32 row][64 B]
    float* ghpart = (float*)(lds + 16384);         // epi overlay over buf1: [8 w][32 row][16]

    const int t    = threadIdx.x;
    const int b0   = blockIdx.x * 32;
    const int kh   = blockIdx.y;                   // K-half
    float* y = kh ? y1 : y0;
    const int w    = t >> 6, lane = t & 63, lr = lane & 15, lg = lane >> 4;

    const int arow  = t >> 4;
    const int spair = t & 15;
    int gr = b0 + arow; if (gr >= Btot) gr = Btot - 1;
    const float* xrow = x + (size_t)gr * KTOT;     // absolute; offsets add kh*768
    const unsigned char* ib = img + (size_t)(w * 24) * 1024 + (size_t)lane * 16;

    // prologue: x chunk (kh*3 + 0)
    float4 ra[4];
    {
        int off = kh * 768 + spair * 16;           // <= 768+240+16 = 1024 < 1344, no clamp
        #pragma unroll
        for (int u = 0; u < 4; ++u) ra[u] = *(const float4*)&xrow[off + u * 4];
    }

    f32x4 acc[3][2], accg[2];
    #pragma unroll
    for (int cf = 0; cf < 3; ++cf) {
        acc[cf][0] = (f32x4){0.f, 0.f, 0.f, 0.f};
        acc[cf][1] = (f32x4){0.f, 0.f, 0.f, 0.f};
    }
    accg[0] = (f32x4){0.f, 0.f, 0.f, 0.f};
    accg[1] = (f32x4){0.f, 0.f, 0.f, 0.f};

    const int wb   = (arow * 64 + spair * 4) ^ ((arow & 7) << 4);
    const int ar0  = (lr * 64 + lg * 16) ^ ((lr & 7) << 4);
    const int ar1  = ((lr + 16) * 64 + lg * 16) ^ ((lr & 7) << 4);

    #pragma unroll
    for (int kc = 0; kc < 3; ++kc) {
        const int ac   = kh * 3 + kc;              // absolute chunk
        const int bufo = (kc & 1) * 16384;
        // publish A(ac) from ra
        {
            const float* rf = (const float*)ra;
            #pragma unroll
            for (int f = 0; f < 8; ++f)
                *(unsigned*)&lds[bufo + f * 2048 + wb] = pack2(rf[f], rf[8 + f]);
        }
        // issue x(ac+1) — 1-deep; latency hidden behind barrier (3 blocks/CU overlap)
        if (kc + 1 < 3) {
            int off = (ac + 1) * 256 + spair * 16;
            if (off > KTOT - 16) off = KTOT - 16;  // s>=168 slots hit zero-B cols
            #pragma unroll
            for (int u = 0; u < 4; ++u) ra[u] = *(const float4*)&xrow[off + u * 4];
        }
        // issue B(ac) — L2-resident; completes at barrier drain
        bf16x8 Br[4];
        #pragma unroll
        for (int cf = 0; cf < 4; ++cf) Br[cf] = *(const bf16x8*)&ib[(cf * 6 + ac) * 1024];
        __syncthreads();
        {
            bf16x8 a0 = *(const bf16x8*)&lds[bufo + w * 2048 + ar0];
            bf16x8 a1 = *(const bf16x8*)&lds[bufo + w * 2048 + ar1];
            #pragma unroll
            for (int cf = 0; cf < 3; ++cf) {
                acc[cf][0] = __builtin_amdgcn_mfma_f32_16x16x32_bf16(a0, Br[cf], acc[cf][0], 0, 0, 0);
                acc[cf][1] = __builtin_amdgcn_mfma_f32_16x16x32_bf16(a1, Br[cf], acc[cf][1], 0, 0, 0);
            }
            accg[0] = __builtin_amdgcn_mfma_f32_16x16x32_bf16(a0, Br[3], accg[0], 0, 0, 0);
            accg[1] = __builtin_amdgcn_mfma_f32_16x16x32_bf16(a1, Br[3], accg[1], 0, 0, 0);
        }
    }

    // ---- TS partial stores (per half): lane-consecutive dwords ----
    #pragma unroll
    for (int cf = 0; cf < 3; ++cf) {
        int c = cf * 16 + lr;
        int base = (c < 24) ? (w * 24 + c) : (192 + w * 24 + (c - 24));
        #pragma unroll
        for (int mf = 0; mf < 2; ++mf) {
            #pragma unroll
            for (int reg = 0; reg < 4; ++reg) {
                int R = b0 + mf * 16 + lg * 4 + reg;
                if (R < Btot) y[(size_t)R * 400 + base] = (mf ? acc[cf][1][reg] : acc[cf][0][reg]);
            }
        }
    }

    // ---- gh partials -> LDS reduce (over buf1; safe: all buf1 reads pre-kc=2-barrier) ----
    #pragma unroll
    for (int mf = 0; mf < 2; ++mf)
        #pragma unroll
        for (int reg = 0; reg < 4; ++reg)
            ghpart[(w * 32 + mf * 16 + lg * 4 + reg) * 16 + lr] = accg[mf][reg];
    __syncthreads();
    {
        int row = t >> 4, col = t & 15;            // 512 = 32x16 exactly
        float s = 0.f;
        #pragma unroll
        for (int f = 0; f < 8; ++f) s += ghpart[f * 512 + row * 16 + col];
        int R = b0 + row;
        if (R < Btot) y[(size_t)R * 400 + 384 + col] = s;
    }
}

// ---------------- VQC: 16 lanes hold the 16 complex amplitudes (verified) ----------------
__device__ __forceinline__ float shflg(float v, int grp, int idx) {
    return __shfl(v, grp + idx, 64);
}

__device__ void vqc_run(const float cq[4], const float sq[4],
                        const float* __restrict__ rc,
                        int l, int grp, float exps[4]) {
    float re = (l == 0) ? 1.f : 0.f;
    float im = 0.f;
    #pragma unroll
    for (int layer = 0; layer < 2; ++layer) {
        #pragma unroll
        for (int q = 0; q < 4; ++q) {
            int m = 1 << (3 - q);
            float pre = shflg(re, grp, l ^ m);
            float pim = shflg(im, grp, l ^ m);
            float sg = (l & m) ? sq[q] : -sq[q];
            re = cq[q] * re + sg * pre;
            im = cq[q] * im + sg * pim;
        }
        #pragma unroll
        for (int q = 0; q < 4; ++q) {
            int m = 1 << (3 - q);
            const float* g = rc + (layer * 4 + q) * 4;
            float A = g[0], B = g[1], C = g[2], D = g[3];
            float pre = shflg(re, grp, l ^ m);
            float pim = shflg(im, grp, l ^ m);
            float car, cai, cpr, cpi;
            if (l & m) { car = A; cai = -B; cpr =  C; cpi = -D; }
            else       { car = A; cai =  B; cpr = -C; cpi = -D; }
            float nre = car * re - cai * im + cpr * pre - cpi * pim;
            float nim = car * im + cai * re + cpr * pim + cpi * pre;
            re = nre; im = nim;
        }
        #pragma unroll
        for (int q = 0; q < 4; ++q) {
            int mc = 1 << (3 - q);
            int mt = 1 << (3 - ((q + 1) & 3));
            float pre = shflg(re, grp, l ^ mt);
            float pim = shflg(im, grp, l ^ mt);
            if (l & mc) { re = pre; im = pim; }
        }
    }
    float prob = re * re + im * im;
    float v0 = (l & 8) ? -prob : prob;
    float v1 = (l & 4) ? -prob : prob;
    float v2 = (l & 2) ? -prob : prob;
    float v3 = (l & 1) ? -prob : prob;
    #pragma unroll
    for (int m = 1; m < 16; m <<= 1) {
        v0 += __shfl_xor(v0, m, 64);
        v1 += __shfl_xor(v1, m, 64);
        v2 += __shfl_xor(v2, m, 64);
        v3 += __shfl_xor(v3, m, 64);
    }
    exps[0] = v0; exps[1] = v1; exps[2] = v2; exps[3] = v3;
}

// ---------------- k_post: sum halves + VQC + fusion (verified r10 chain) ----------------
__global__ __launch_bounds__(256)
void k_post(const float* __restrict__ y0, const float* __restrict__ y1,
            const float* __restrict__ rotc,
            const float* __restrict__ cgin, const float* __restrict__ h0_b,
            const float* __restrict__ crz_w, const float* __restrict__ crz_b,
            const float* __restrict__ cn_w, const float* __restrict__ cn_b,
            const float* __restrict__ expand_w, const float* __restrict__ expand_b,
            const float* __restrict__ mod_w, const float* __restrict__ mod_b,
            const float* __restrict__ trend_b, const float* __restrict__ seasonal_b,
            const float* __restrict__ fusion_alpha,
            float* __restrict__ out, int Btot)
{
    __shared__ float yb[16 * 400];
    __shared__ float modt[16 * 25];
    const int t  = threadIdx.x;
    const int b0 = blockIdx.x * 16;

    // stage y tile = y0 + y1 (coalesced float4)
    #pragma unroll
    for (int i = 0; i < 7; ++i) {
        int idx = t + i * 256;                 // 1600 float4 units
        if (idx < 1600) {
            int r = idx / 100, cu = idx % 100;
            int R = b0 + r; if (R >= Btot) R = Btot - 1;
            float4 a = *(const float4*)&y0[(size_t)R * 400 + cu * 4];
            float4 b = *(const float4*)&y1[(size_t)R * 400 + cu * 4];
            float4 s; s.x = a.x + b.x; s.y = a.y + b.y; s.z = a.z + b.z; s.w = a.w + b.w;
            *(float4*)&yb[r * 400 + cu * 4] = s;
        }
    }
    __syncthreads();

    {
        const int rl  = t >> 4;
        const int l   = t & 15;
        const int lane = t & 63;
        const int grp = lane & 48;
        float gin[HID], h0v[HID];
        #pragma unroll
        for (int h = 0; h < HID; ++h) {
            gin[h] = ftanh(yb[rl * 400 + 384 + h] + cgin[h]);
            h0v[h] = ftanh(yb[rl * 400 + 392 + h] + h0_b[h]);
        }
        float rz[4];
        #pragma unroll
        for (int q = 0; q < 4; ++q) {
            float a = crz_b[q];
            #pragma unroll
            for (int k = 0; k < 8; ++k) a = fmaf(gin[k], crz_w[q * 16 + k], a);
            #pragma unroll
            for (int k = 0; k < 8; ++k) a = fmaf(h0v[k], crz_w[q * 16 + 8 + k], a);
            rz[q] = ftanh(a) * PI_F;
        }
        float cq[4], sq[4];
        #pragma unroll
        for (int q = 0; q < 4; ++q) { cq[q] = __cosf(0.5f * rz[q]); sq[q] = __sinf(0.5f * rz[q]); }

        float er[4], ez[4];
        vqc_run(cq, sq, rotc + 0 * 32, l, grp, er);
        vqc_run(cq, sq, rotc + 1 * 32, l, grp, ez);

        float rr[HID], zz[HID];
        #pragma unroll
        for (int h = 0; h < HID; ++h) {
            float a = expand_b[h], b = expand_b[h];
            #pragma unroll
            for (int q = 0; q < 4; ++q) {
                a = fmaf(er[q], expand_w[h * 4 + q], a);
                b = fmaf(ez[q], expand_w[h * 4 + q], b);
            }
            rr[h] = sigm(a);
            zz[h] = sigm(b);
        }
        float ni[4];
        #pragma unroll
        for (int q = 0; q < 4; ++q) {
            float a = cn_b[q];
            #pragma unroll
            for (int k = 0; k < 8; ++k) a = fmaf(rr[k] * h0v[k], cn_w[q * 16 + k], a);
            #pragma unroll
            for (int k = 0; k < 8; ++k) a = fmaf(gin[k], cn_w[q * 16 + 8 + k], a);
            ni[q] = ftanh(a) * PI_F;
        }
        #pragma unroll
        for (int q = 0; q < 4; ++q) { cq[q] = __cosf(0.5f * ni[q]); sq[q] = __sinf(0.5f * ni[q]); }
        float en[4];
        vqc_run(cq, sq, rotc + 2 * 32, l, grp, en);

        float hn[HID];
        #pragma unroll
        for (int h = 0; h < HID; ++h) {
            float a = expand_b[h];
            #pragma unroll
            for (int q = 0; q < 4; ++q) a = fmaf(en[q], expand_w[h * 4 + q], a);
            float nn = ftanh(a);
            hn[h] = (1.f - zz[h]) * nn + zz[h] * h0v[h];
        }
        int pp = l;
        float a = mod_b[pp];
        #pragma unroll
        for (int h = 0; h < HID; ++h) a = fmaf(hn[h], mod_w[pp * 8 + h], a);
        modt[rl * 25 + pp] = ftanh(a);
        if (l < 8) {
            pp = l + 16;
            a = mod_b[pp];
            #pragma unroll
            for (int h = 0; h < HID; ++h) a = fmaf(hn[h], mod_w[pp * 8 + h], a);
            modt[rl * 25 + pp] = ftanh(a);
        }
    }
    __syncthreads();

    const float alpha = sigm(fusion_alpha[0]);
    #pragma unroll
    for (int i = 0; i < 12; ++i) {
        int idx = t + i * 256;                 // 16 rows x 192 outs
        int r = idx / 192, o = idx % 192;
        int R = b0 + r;
        if (R < Btot) {
            int p = o >> 3, f = o & 7;
            float T = yb[r * 400 + f * 24 + p];
            float S = yb[r * 400 + 192 + f * 24 + p];
            float md = modt[r * 25 + p];
            out[(size_t)R * 192 + o] = alpha * ((S + seasonal_b[p]) * (1.f + md))
                                     + (1.f - alpha) * (T + trend_b[p]);
        }
    }
}

extern "C" void kernel_launch(void* const* d_in, const int* in_sizes, int n_in,
                              void* d_out, int out_size, void* d_ws, size_t ws_size,
                              hipStream_t stream) {
    const float* x          = (const float*)d_in[0];
    const float* decomp_w   = (const float*)d_in[1];
    const float* trend_w    = (const float*)d_in[2];
    const float* trend_b    = (const float*)d_in[3];
    const float* seasonal_w = (const float*)d_in[4];
    const float* seasonal_b = (const float*)d_in[5];
    const float* h0_w       = (const float*)d_in[6];
    const float* h0_b       = (const float*)d_in[7];
    const float* ta_w       = (const float*)d_in[8];
    const float* ta_b       = (const float*)d_in[9];
    const float* sc_w       = (const float*)d_in[10];
    const float* sc_b       = (const float*)d_in[11];
    const float* crz_w      = (const float*)d_in[12];
    const float* crz_b      = (const float*)d_in[13];
    const float* cn_w       = (const float*)d_in[14];
    const float* cn_b       = (const float*)d_in[15];
    const float* vqc_r      = (const float*)d_in[16];
    const float* vqc_u      = (const float*)d_in[17];
    const float* vqc_c      = (const float*)d_in[18];
    const float* expand_w   = (const float*)d_in[19];
    const float* expand_b   = (const float*)d_in[20];
    const float* mod_w      = (const float*)d_in[21];
    const float* mod_b      = (const float*)d_in[22];
    const float* fus_a      = (const float*)d_in[23];
    float* out = (float*)d_out;

    float* ws   = (float*)d_ws;
    float* rotc = ws + WS_ROTC;
    float* cgin = ws + WS_CGIN;
    float* Wt   = ws + WS_WT;
    float* y0   = ws + WS_Y0;
    float* y1   = ws + WS_Y1;
    unsigned char* img = (unsigned char*)d_ws + WS_IMG_BYTE;

    const int Btot = in_sizes[0] / (SEQ * NF);

    k_compose<<<(SEQ * 640 + 255) / 256, 256, 0, stream>>>(decomp_w, trend_w, seasonal_w, ta_w, Wt);
    k_img<<<49, 256, 0, stream>>>(Wt, sc_w, h0_w, vqc_r, vqc_u, vqc_c, sc_b, ta_b,
                                  rotc, cgin, img);

    dim3 ggrid((Btot + 31) / 32, 2);
    k_gemm<<<ggrid, 512, 0, stream>>>(x, img, y0, y1, Btot);

    k_post<<<(Btot + 15) / 16, 256, 0, stream>>>(y0, y1, rotc, cgin, h0_b,
                                                 crz_w, crz_b, cn_w, cn_b,
                                                 expand_w, expand_b, mod_w, mod_b,
                                                 trend_b, seasonal_b, fus_a, out, Btot);
}

// Round 13
// 60.556 us; speedup vs baseline: 1.0815x; 1.0815x over previous
//
#include <hip/hip_runtime.h>
#include <hip/hip_bf16.h>
#include <cmath>

#define SEQ   168
#define NF    8
#define PRED  24
#define HID   8
#define KTOT  1344          // SEQ*NF (x row flat length)
#define NSCH  6             // s-chunks of 32 (K padded to 192)
#define PI_F  3.14159265358979323846f

// ---------------- workspace layout ----------------
#define WS_ROTC     256      // floats: 3*2*4*4 rot coeffs
#define WS_CGIN     512      // floats: 8 gin constants
#define WS_WT       1024     // floats: 168*640 composed weights, ends 108544
#define WS_Y        400000   // floats: y[16384][400] = 26.2 MB
#define WS_IMG_BYTE 524288   // bytes: lane-exact B image 192*1024 = 196608

typedef __attribute__((ext_vector_type(8))) short bf16x8;
typedef __attribute__((ext_vector_type(4))) float f32x4;

__device__ __forceinline__ float frcp(float x)  { return __builtin_amdgcn_rcpf(x); }
__device__ __forceinline__ float ftanh(float x) {
    float xc = fminf(fmaxf(x, -15.f), 15.f);
    float e  = __expf(2.f * xc);
    return (e - 1.f) * frcp(e + 1.f);
}
__device__ __forceinline__ float sigm(float x) { return frcp(1.f + __expf(-x)); }
__device__ __forceinline__ unsigned short f2bf(float f) {
    __hip_bfloat16 h = __float2bfloat16(f);
    return __builtin_bit_cast(unsigned short, h);
}
__device__ __forceinline__ unsigned pack2(float a, float b) {
    return (unsigned)f2bf(a) | ((unsigned)f2bf(b) << 16);
}

// ---------------- compose conv into projection weights (f32, verified r1-r12) ----------------
__global__ void k_compose(const float* __restrict__ decomp_w,
                          const float* __restrict__ trend_w,
                          const float* __restrict__ seasonal_w,
                          const float* __restrict__ ta_w,
                          float* __restrict__ Wt) {
    __shared__ float dwsh[NF * 25];
    int t = threadIdx.x;
    if (t < NF) {
        const float* row = decomp_w + t * 25;
        float m = row[0];
        for (int k = 1; k < 25; ++k) m = fmaxf(m, row[k]);
        float e[25]; float sum = 0.f;
        for (int k = 0; k < 25; ++k) { e[k] = expf(row[k] - m); sum += e[k]; }
        float inv = 1.f / sum;
        for (int k = 0; k < 25; ++k) dwsh[t * 25 + k] = e[k] * inv;
    }
    __syncthreads();
    int n = blockIdx.x * 256 + t;
    if (n >= SEQ * 640) return;
    int sx  = n / 640;
    int col = n % 640;
    int j = col >> 3;
    int f = col & 7;
    const float* dwf = dwsh + f * 25;
    const float* wsel;
    int isTrend = 0;
    if (j < 24)      { wsel = trend_w    + j        * SEQ; isTrend = 1; }
    else if (j < 48) { wsel = seasonal_w + (j - 24) * SEQ; }
    else             { wsel = ta_w       + (j - 48) * SEQ; }
    float acc = 0.f;
    if (sx == 0) {
        for (int s = 0; s <= 12; ++s) {
            float cw = 0.f;
            for (int k = 0; k <= 12 - s; ++k) cw += dwf[k];
            acc = fmaf(cw, wsel[s], acc);
        }
    } else if (sx == 167) {
        for (int s = 155; s < 168; ++s) {
            float cw = 0.f;
            for (int k = 179 - s; k < 25; ++k) cw += dwf[k];
            acc = fmaf(cw, wsel[s], acc);
        }
    } else {
        int lo = sx - 12; if (lo < 0) lo = 0;
        int hi = sx + 12; if (hi > 167) hi = 167;
        for (int s = lo; s <= hi; ++s) acc = fmaf(dwf[sx - s + 12], wsel[s], acc);
    }
    Wt[sx * 640 + col] = isTrend ? acc : (wsel[sx] - acc);
}

// ---------------- lane-exact B image + rotc/cgin (verified r10) ----------------
__global__ void k_img(const float* __restrict__ Wt, const float* __restrict__ sc_w,
                      const float* __restrict__ h0_w,
                      const float* __restrict__ vr, const float* __restrict__ vu,
                      const float* __restrict__ vc,
                      const float* __restrict__ sc_b, const float* __restrict__ ta_b,
                      float* __restrict__ rotc, float* __restrict__ cgin,
                      unsigned char* __restrict__ imgb) {
    int idx = blockIdx.x * 256 + threadIdx.x;
    if (idx < 12288) {
        int lane = idx & 63;
        int rest = idx >> 6;          // (f*4+cf)*6+ks
        int ks = rest % 6;
        int fc = rest / 6;
        int cf = fc & 3, f = fc >> 2;
        int lr = lane & 15, lg = lane >> 4;
        unsigned short vals[8];
        #pragma unroll
        for (int e = 0; e < 8; ++e) {
            int k = ks * 32 + lg * 8 + e;           // = s
            float val = 0.f;
            if (k < SEQ) {
                if (cf < 3) {
                    int c = cf * 16 + lr;
                    int ts = (c >= 24);
                    int p  = ts ? (c - 24) : c;
                    val = Wt[k * 640 + ts * 192 + p * 8 + f];
                } else if (lr < 8) {
                    float a = 0.f;
                    for (int cc = 0; cc < 32; ++cc)
                        a = fmaf(sc_w[lr * 256 + f * 32 + cc], Wt[k * 640 + 384 + cc * 8 + f], a);
                    val = a;
                } else if (f == 7) {
                    const int LIDX[11] = {167,166,165,164,163,162,145,144,143,1,0};
                    #pragma unroll
                    for (int i = 0; i < 11; ++i)
                        if (k == LIDX[i]) val = h0_w[(lr - 8) * 11 + i];
                }
            }
            vals[e] = f2bf(val);
        }
        uint4 o;
        o.x = (unsigned)vals[0] | ((unsigned)vals[1] << 16);
        o.y = (unsigned)vals[2] | ((unsigned)vals[3] << 16);
        o.z = (unsigned)vals[4] | ((unsigned)vals[5] << 16);
        o.w = (unsigned)vals[6] | ((unsigned)vals[7] << 16);
        *(uint4*)(imgb + (size_t)rest * 1024 + lane * 16) = o;
    } else if (blockIdx.x == 48) {
        int t = threadIdx.x;
        if (t >= 64 && t < 88) {
            int n = t - 64;
            int v = n / 8, rest = n % 8;
            const float* w = (v == 0 ? vr : (v == 1 ? vu : vc)) + rest * 3;
            float phi = w[0], th = w[1], om = w[2];
            float c = cosf(0.5f * th), s = sinf(0.5f * th);
            float ap = -0.5f * (phi + om);
            float am =  0.5f * (phi - om);
            float* o = rotc + n * 4;
            o[0] = cosf(ap) * c;
            o[1] = sinf(ap) * c;
            o[2] = cosf(am) * s;
            o[3] = sinf(am) * s;
        } else if (t >= 96 && t < 104) {
            int h = t - 96;
            float a = sc_b[h];
            for (int cc = 0; cc < 32; ++cc) {
                float s = 0.f;
                for (int f = 0; f < 8; ++f) s += sc_w[h * 256 + f * 32 + cc];
                a = fmaf(ta_b[cc], s, a);
            }
            cgin[h] = a;
        }
    }
}

// ---------------- k_gemm: SMALL blocks (256 thr, M=16), high residency ----------------
// grid 1024; 4 waves, wave w = features {2w, 2w+1}. LDS 16KB (A dbuf 2x8KB, ghpart
// overlays buf0 post-kc5-barrier). Same verified math/layout as r9/r10.
__global__ __launch_bounds__(256, 4)
void k_gemm(const float* __restrict__ x, const unsigned char* __restrict__ img,
            float* __restrict__ y, int Btot)
{
    __shared__ unsigned char lds[16384];           // A dbuf [2][8 f][16 row][64 B]
    float* ghpart = (float*)lds;                   // overlay buf0: [8 f][16 row][16]

    const int t    = threadIdx.x;
    const int b0   = blockIdx.x * 16;
    const int w    = t >> 6, lane = t & 63, lr = lane & 15, lg = lane >> 4;
    const int f0   = 2 * w, f1 = 2 * w + 1;

    const int arow  = t >> 4;                      // 0..15
    const int spair = t & 15;
    int gr = b0 + arow; if (gr >= Btot) gr = Btot - 1;
    const float* xrow = x + (size_t)gr * KTOT;

    // x prologue (chunk 0)
    float4 ra[4];
    #pragma unroll
    for (int u = 0; u < 4; ++u) ra[u] = *(const float4*)&xrow[spair * 16 + u * 4];

    f32x4 acc[2][3], accg[2];
    #pragma unroll
    for (int ff = 0; ff < 2; ++ff) {
        #pragma unroll
        for (int cf = 0; cf < 3; ++cf) acc[ff][cf] = (f32x4){0.f, 0.f, 0.f, 0.f};
        accg[ff] = (f32x4){0.f, 0.f, 0.f, 0.f};
    }

    const int wb   = (arow * 64 + spair * 4) ^ ((arow & 7) << 4);
    const int ard  = (lr * 64 + lg * 16) ^ ((lr & 7) << 4);

    #pragma unroll
    for (int kc = 0; kc < NSCH; ++kc) {
        const int bufo = (kc & 1) * 8192;
        // publish A(kc): 8 ds_write_b32, per-feature planes [f][row][s]
        {
            const float* rf = (const float*)ra;
            #pragma unroll
            for (int f = 0; f < 8; ++f)
                *(unsigned*)&lds[bufo + f * 1024 + wb] = pack2(rf[f], rf[8 + f]);
        }
        // x prefetch (kc+1)
        if (kc + 1 < NSCH) {
            int off = (kc + 1) * 256 + spair * 16;
            if (off > KTOT - 16) off = KTOT - 16;  // pad s>=168: zero-B cols
            #pragma unroll
            for (int u = 0; u < 4; ++u) ra[u] = *(const float4*)&xrow[off + u * 4];
        }
        // B(kc) for this wave's two features (L2-resident, lane-exact)
        bf16x8 Br[8];
        #pragma unroll
        for (int ff = 0; ff < 2; ++ff)
            #pragma unroll
            for (int cf = 0; cf < 4; ++cf)
                Br[ff * 4 + cf] = *(const bf16x8*)&img[
                    (size_t)(((2 * w + ff) * 4 + cf) * 6 + kc) * 1024 + (size_t)lane * 16];
        __syncthreads();
        {
            bf16x8 a0 = *(const bf16x8*)&lds[bufo + f0 * 1024 + ard];
            bf16x8 a1 = *(const bf16x8*)&lds[bufo + f1 * 1024 + ard];
            #pragma unroll
            for (int cf = 0; cf < 3; ++cf) {
                acc[0][cf] = __builtin_amdgcn_mfma_f32_16x16x32_bf16(a0, Br[cf],     acc[0][cf], 0, 0, 0);
                acc[1][cf] = __builtin_amdgcn_mfma_f32_16x16x32_bf16(a1, Br[4 + cf], acc[1][cf], 0, 0, 0);
            }
            accg[0] = __builtin_amdgcn_mfma_f32_16x16x32_bf16(a0, Br[3], accg[0], 0, 0, 0);
            accg[1] = __builtin_amdgcn_mfma_f32_16x16x32_bf16(a1, Br[7], accg[1], 0, 0, 0);
        }
    }

    // ---- TS stores: lane-consecutive dwords (T/S split layout, verified r10) ----
    #pragma unroll
    for (int ff = 0; ff < 2; ++ff) {
        int f = 2 * w + ff;
        #pragma unroll
        for (int cf = 0; cf < 3; ++cf) {
            int c = cf * 16 + lr;
            int base = (c < 24) ? (f * 24 + c) : (192 + f * 24 + (c - 24));
            #pragma unroll
            for (int reg = 0; reg < 4; ++reg) {
                int R = b0 + lg * 4 + reg;
                if (R < Btot) y[(size_t)R * 400 + base] = acc[ff][cf][reg];
            }
        }
    }

    // ---- gh partials -> LDS reduce (overlay buf0; safe: buf0 last read kc=4, kc=5 barrier) ----
    #pragma unroll
    for (int ff = 0; ff < 2; ++ff) {
        int f = 2 * w + ff;
        #pragma unroll
        for (int reg = 0; reg < 4; ++reg)
            ghpart[(f * 16 + lg * 4 + reg) * 16 + lr] = accg[ff][reg];
    }
    __syncthreads();
    {
        int row = t >> 4, col = t & 15;            // 256 = 16x16 exactly
        float s = 0.f;
        #pragma unroll
        for (int f = 0; f < 8; ++f) s += ghpart[f * 256 + row * 16 + col];
        int R = b0 + row;
        if (R < Btot) y[(size_t)R * 400 + 384 + col] = s;
    }
}

// ---------------- VQC: 16 lanes hold the 16 complex amplitudes (verified) ----------------
__device__ __forceinline__ float shflg(float v, int grp, int idx) {
    return __shfl(v, grp + idx, 64);
}

__device__ void vqc_run(const float cq[4], const float sq[4],
                        const float* __restrict__ rc,
                        int l, int grp, float exps[4]) {
    float re = (l == 0) ? 1.f : 0.f;
    float im = 0.f;
    #pragma unroll
    for (int layer = 0; layer < 2; ++layer) {
        #pragma unroll
        for (int q = 0; q < 4; ++q) {
            int m = 1 << (3 - q);
            float pre = shflg(re, grp, l ^ m);
            float pim = shflg(im, grp, l ^ m);
            float sg = (l & m) ? sq[q] : -sq[q];
            re = cq[q] * re + sg * pre;
            im = cq[q] * im + sg * pim;
        }
        #pragma unroll
        for (int q = 0; q < 4; ++q) {
            int m = 1 << (3 - q);
            const float* g = rc + (layer * 4 + q) * 4;
            float A = g[0], B = g[1], C = g[2], D = g[3];
            float pre = shflg(re, grp, l ^ m);
            float pim = shflg(im, grp, l ^ m);
            float car, cai, cpr, cpi;
            if (l & m) { car = A; cai = -B; cpr =  C; cpi = -D; }
            else       { car = A; cai =  B; cpr = -C; cpi = -D; }
            float nre = car * re - cai * im + cpr * pre - cpi * pim;
            float nim = car * im + cai * re + cpr * pim + cpi * pre;
            re = nre; im = nim;
        }
        #pragma unroll
        for (int q = 0; q < 4; ++q) {
            int mc = 1 << (3 - q);
            int mt = 1 << (3 - ((q + 1) & 3));
            float pre = shflg(re, grp, l ^ mt);
            float pim = shflg(im, grp, l ^ mt);
            if (l & mc) { re = pre; im = pim; }
        }
    }
    float prob = re * re + im * im;
    float v0 = (l & 8) ? -prob : prob;
    float v1 = (l & 4) ? -prob : prob;
    float v2 = (l & 2) ? -prob : prob;
    float v3 = (l & 1) ? -prob : prob;
    #pragma unroll
    for (int m = 1; m < 16; m <<= 1) {
        v0 += __shfl_xor(v0, m, 64);
        v1 += __shfl_xor(v1, m, 64);
        v2 += __shfl_xor(v2, m, 64);
        v3 += __shfl_xor(v3, m, 64);
    }
    exps[0] = v0; exps[1] = v1; exps[2] = v2; exps[3] = v3;
}

// ---------------- k_post: VQC + fusion, 16 rows/block (verified r10) ----------------
__global__ __launch_bounds__(256)
void k_post(const float* __restrict__ y, const float* __restrict__ rotc,
            const float* __restrict__ cgin, const float* __restrict__ h0_b,
            const float* __restrict__ crz_w, const float* __restrict__ crz_b,
            const float* __restrict__ cn_w, const float* __restrict__ cn_b,
            const float* __restrict__ expand_w, const float* __restrict__ expand_b,
            const float* __restrict__ mod_w, const float* __restrict__ mod_b,
            const float* __restrict__ trend_b, const float* __restrict__ seasonal_b,
            const float* __restrict__ fusion_alpha,
            float* __restrict__ out, int Btot)
{
    __shared__ float yb[16 * 400];
    __shared__ float modt[16 * 25];
    const int t  = threadIdx.x;
    const int b0 = blockIdx.x * 16;

    #pragma unroll
    for (int i = 0; i < 7; ++i) {
        int idx = t + i * 256;                 // 1600 float4 units
        if (idx < 1600) {
            int r = idx / 100, cu = idx % 100;
            int R = b0 + r; if (R >= Btot) R = Btot - 1;
            *(float4*)&yb[r * 400 + cu * 4] = *(const float4*)&y[(size_t)R * 400 + cu * 4];
        }
    }
    __syncthreads();

    {
        const int rl  = t >> 4;
        const int l   = t & 15;
        const int lane = t & 63;
        const int grp = lane & 48;
        float gin[HID], h0v[HID];
        #pragma unroll
        for (int h = 0; h < HID; ++h) {
            gin[h] = ftanh(yb[rl * 400 + 384 + h] + cgin[h]);
            h0v[h] = ftanh(yb[rl * 400 + 392 + h] + h0_b[h]);
        }
        float rz[4];
        #pragma unroll
        for (int q = 0; q < 4; ++q) {
            float a = crz_b[q];
            #pragma unroll
            for (int k = 0; k < 8; ++k) a = fmaf(gin[k], crz_w[q * 16 + k], a);
            #pragma unroll
            for (int k = 0; k < 8; ++k) a = fmaf(h0v[k], crz_w[q * 16 + 8 + k], a);
            rz[q] = ftanh(a) * PI_F;
        }
        float cq[4], sq[4];
        #pragma unroll
        for (int q = 0; q < 4; ++q) { cq[q] = __cosf(0.5f * rz[q]); sq[q] = __sinf(0.5f * rz[q]); }

        float er[4], ez[4];
        vqc_run(cq, sq, rotc + 0 * 32, l, grp, er);
        vqc_run(cq, sq, rotc + 1 * 32, l, grp, ez);

        float rr[HID], zz[HID];
        #pragma unroll
        for (int h = 0; h < HID; ++h) {
            float a = expand_b[h], b = expand_b[h];
            #pragma unroll
            for (int q = 0; q < 4; ++q) {
                a = fmaf(er[q], expand_w[h * 4 + q], a);
                b = fmaf(ez[q], expand_w[h * 4 + q], b);
            }
            rr[h] = sigm(a);
            zz[h] = sigm(b);
        }
        float ni[4];
        #pragma unroll
        for (int q = 0; q < 4; ++q) {
            float a = cn_b[q];
            #pragma unroll
            for (int k = 0; k < 8; ++k) a = fmaf(rr[k] * h0v[k], cn_w[q * 16 + k], a);
            #pragma unroll
            for (int k = 0; k < 8; ++k) a = fmaf(gin[k], cn_w[q * 16 + 8 + k], a);
            ni[q] = ftanh(a) * PI_F;
        }
        #pragma unroll
        for (int q = 0; q < 4; ++q) { cq[q] = __cosf(0.5f * ni[q]); sq[q] = __sinf(0.5f * ni[q]); }
        float en[4];
        vqc_run(cq, sq, rotc + 2 * 32, l, grp, en);

        float hn[HID];
        #pragma unroll
        for (int h = 0; h < HID; ++h) {
            float a = expand_b[h];
            #pragma unroll
            for (int q = 0; q < 4; ++q) a = fmaf(en[q], expand_w[h * 4 + q], a);
            float nn = ftanh(a);
            hn[h] = (1.f - zz[h]) * nn + zz[h] * h0v[h];
        }
        int pp = l;
        float a = mod_b[pp];
        #pragma unroll
        for (int h = 0; h < HID; ++h) a = fmaf(hn[h], mod_w[pp * 8 + h], a);
        modt[rl * 25 + pp] = ftanh(a);
        if (l < 8) {
            pp = l + 16;
            a = mod_b[pp];
            #pragma unroll
            for (int h = 0; h < HID; ++h) a = fmaf(hn[h], mod_w[pp * 8 + h], a);
            modt[rl * 25 + pp] = ftanh(a);
        }
    }
    __syncthreads();

    const float alpha = sigm(fusion_alpha[0]);
    #pragma unroll
    for (int i = 0; i < 12; ++i) {
        int idx = t + i * 256;                 // 16 rows x 192 outs
        int r = idx / 192, o = idx % 192;
        int R = b0 + r;
        if (R < Btot) {
            int p = o >> 3, f = o & 7;
            float T = yb[r * 400 + f * 24 + p];
            float S = yb[r * 400 + 192 + f * 24 + p];
            float md = modt[r * 25 + p];
            out[(size_t)R * 192 + o] = alpha * ((S + seasonal_b[p]) * (1.f + md))
                                     + (1.f - alpha) * (T + trend_b[p]);
        }
    }
}

extern "C" void kernel_launch(void* const* d_in, const int* in_sizes, int n_in,
                              void* d_out, int out_size, void* d_ws, size_t ws_size,
                              hipStream_t stream) {
    const float* x          = (const float*)d_in[0];
    const float* decomp_w   = (const float*)d_in[1];
    const float* trend_w    = (const float*)d_in[2];
    const float* trend_b    = (const float*)d_in[3];
    const float* seasonal_w = (const float*)d_in[4];
    const float* seasonal_b = (const float*)d_in[5];
    const float* h0_w       = (const float*)d_in[6];
    const float* h0_b       = (const float*)d_in[7];
    const float* ta_w       = (const float*)d_in[8];
    const float* ta_b       = (const float*)d_in[9];
    const float* sc_w       = (const float*)d_in[10];
    const float* sc_b       = (const float*)d_in[11];
    const float* crz_w      = (const float*)d_in[12];
    const float* crz_b      = (const float*)d_in[13];
    const float* cn_w       = (const float*)d_in[14];
    const float* cn_b       = (const float*)d_in[15];
    const float* vqc_r      = (const float*)d_in[16];
    const float* vqc_u      = (const float*)d_in[17];
    const float* vqc_c      = (const float*)d_in[18];
    const float* expand_w   = (const float*)d_in[19];
    const float* expand_b   = (const float*)d_in[20];
    const float* mod_w      = (const float*)d_in[21];
    const float* mod_b      = (const float*)d_in[22];
    const float* fus_a      = (const float*)d_in[23];
    float* out = (float*)d_out;

    float* ws   = (float*)d_ws;
    float* rotc = ws + WS_ROTC;
    float* cgin = ws + WS_CGIN;
    float* Wt   = ws + WS_WT;
    float* y    = ws + WS_Y;
    unsigned char* img = (unsigned char*)d_ws + WS_IMG_BYTE;

    const int Btot = in_sizes[0] / (SEQ * NF);

    k_compose<<<(SEQ * 640 + 255) / 256, 256, 0, stream>>>(decomp_w, trend_w, seasonal_w, ta_w, Wt);
    k_img<<<49, 256, 0, stream>>>(Wt, sc_w, h0_w, vqc_r, vqc_u, vqc_c, sc_b, ta_b,
                                  rotc, cgin, img);

    k_gemm<<<(Btot + 15) / 16, 256, 0, stream>>>(x, img, y, Btot);

    k_post<<<(Btot + 15) / 16, 256, 0, stream>>>(y, rotc, cgin, h0_b,
                                                 crz_w, crz_b, cn_w, cn_b,
                                                 expand_w, expand_b, mod_w, mod_b,
                                                 trend_b, seasonal_b, fus_a, out, Btot);
}

// Round 14
// 49.446 us; speedup vs baseline: 1.3245x; 1.2247x over previous
//
#include <hip/hip_runtime.h>
#include <hip/hip_bf16.h>
#include <cmath>

#define SEQ   168
#define NF    8
#define PRED  24
#define HID   8
#define KTOT  1344          // SEQ*NF (x row flat length)
#define NSCH  6             // s-chunks of 32 (K padded to 192)
#define PI_F  3.14159265358979323846f

// ---------------- workspace layout ----------------
#define WS_ROTC     256      // floats: 3*2*4*4 rot coeffs
#define WS_CGIN     512      // floats: 8 gin constants
#define WS_WT       1024     // floats: 168*640 composed weights, ends 108544
#define WS_IMG_BYTE 524288   // bytes: lane-exact B image 192*1024 = 196608

typedef __attribute__((ext_vector_type(8))) short bf16x8;
typedef __attribute__((ext_vector_type(4))) float f32x4;

__device__ __forceinline__ float frcp(float x)  { return __builtin_amdgcn_rcpf(x); }
__device__ __forceinline__ float ftanh(float x) {
    float xc = fminf(fmaxf(x, -15.f), 15.f);
    float e  = __expf(2.f * xc);
    return (e - 1.f) * frcp(e + 1.f);
}
__device__ __forceinline__ float sigm(float x) { return frcp(1.f + __expf(-x)); }
__device__ __forceinline__ unsigned short f2bf(float f) {
    __hip_bfloat16 h = __float2bfloat16(f);
    return __builtin_bit_cast(unsigned short, h);
}
__device__ __forceinline__ unsigned pack2(float a, float b) {
    return (unsigned)f2bf(a) | ((unsigned)f2bf(b) << 16);
}

// ---------------- compose conv into projection weights (f32, verified r1-r13) ----------------
__global__ void k_compose(const float* __restrict__ decomp_w,
                          const float* __restrict__ trend_w,
                          const float* __restrict__ seasonal_w,
                          const float* __restrict__ ta_w,
                          float* __restrict__ Wt) {
    __shared__ float dwsh[NF * 25];
    int t = threadIdx.x;
    if (t < NF) {
        const float* row = decomp_w + t * 25;
        float m = row[0];
        for (int k = 1; k < 25; ++k) m = fmaxf(m, row[k]);
        float e[25]; float sum = 0.f;
        for (int k = 0; k < 25; ++k) { e[k] = expf(row[k] - m); sum += e[k]; }
        float inv = 1.f / sum;
        for (int k = 0; k < 25; ++k) dwsh[t * 25 + k] = e[k] * inv;
    }
    __syncthreads();
    int n = blockIdx.x * 256 + t;
    if (n >= SEQ * 640) return;
    int sx  = n / 640;
    int col = n % 640;
    int j = col >> 3;
    int f = col & 7;
    const float* dwf = dwsh + f * 25;
    const float* wsel;
    int isTrend = 0;
    if (j < 24)      { wsel = trend_w    + j        * SEQ; isTrend = 1; }
    else if (j < 48) { wsel = seasonal_w + (j - 24) * SEQ; }
    else             { wsel = ta_w       + (j - 48) * SEQ; }
    float acc = 0.f;
    if (sx == 0) {
        for (int s = 0; s <= 12; ++s) {
            float cw = 0.f;
            for (int k = 0; k <= 12 - s; ++k) cw += dwf[k];
            acc = fmaf(cw, wsel[s], acc);
        }
    } else if (sx == 167) {
        for (int s = 155; s < 168; ++s) {
            float cw = 0.f;
            for (int k = 179 - s; k < 25; ++k) cw += dwf[k];
            acc = fmaf(cw, wsel[s], acc);
        }
    } else {
        int lo = sx - 12; if (lo < 0) lo = 0;
        int hi = sx + 12; if (hi > 167) hi = 167;
        for (int s = lo; s <= hi; ++s) acc = fmaf(dwf[sx - s + 12], wsel[s], acc);
    }
    Wt[sx * 640 + col] = isTrend ? acc : (wsel[sx] - acc);
}

// ---------------- lane-exact B image, INTERLEAVED T/S (verified r7/r8) + rotc/cgin ----------------
// [(f*4+cf)*6+ks] blocks of 1024 B; lane l holds 8 bf16 at byte l*16: B[col][k=ks*32+lg*8+e]
// cf<3: col=cf*16+lr -> Wt[k*640+(col&1)*192+(col>>1)*8+f]
// cf=3: lr<8 gin h=lr (sc_w folded per feature); lr>=8 h0 h=lr-8 (f==7 lags)
__global__ void k_img(const float* __restrict__ Wt, const float* __restrict__ sc_w,
                      const float* __restrict__ h0_w,
                      const float* __restrict__ vr, const float* __restrict__ vu,
                      const float* __restrict__ vc,
                      const float* __restrict__ sc_b, const float* __restrict__ ta_b,
                      float* __restrict__ rotc, float* __restrict__ cgin,
                      unsigned char* __restrict__ imgb) {
    int idx = blockIdx.x * 256 + threadIdx.x;
    if (idx < 12288) {
        int lane = idx & 63;
        int rest = idx >> 6;          // (f*4+cf)*6+ks
        int ks = rest % 6;
        int fc = rest / 6;
        int cf = fc & 3, f = fc >> 2;
        int lr = lane & 15, lg = lane >> 4;
        unsigned short vals[8];
        #pragma unroll
        for (int e = 0; e < 8; ++e) {
            int k = ks * 32 + lg * 8 + e;           // = s
            float val = 0.f;
            if (k < SEQ) {
                if (cf < 3) {
                    int col = cf * 16 + lr;
                    val = Wt[k * 640 + (col & 1) * 192 + (col >> 1) * 8 + f];
                } else if (lr < 8) {
                    float a = 0.f;
                    for (int cc = 0; cc < 32; ++cc)
                        a = fmaf(sc_w[lr * 256 + f * 32 + cc], Wt[k * 640 + 384 + cc * 8 + f], a);
                    val = a;
                } else if (f == 7) {
                    const int LIDX[11] = {167,166,165,164,163,162,145,144,143,1,0};
                    #pragma unroll
                    for (int i = 0; i < 11; ++i)
                        if (k == LIDX[i]) val = h0_w[(lr - 8) * 11 + i];
                }
            }
            vals[e] = f2bf(val);
        }
        uint4 o;
        o.x = (unsigned)vals[0] | ((unsigned)vals[1] << 16);
        o.y = (unsigned)vals[2] | ((unsigned)vals[3] << 16);
        o.z = (unsigned)vals[4] | ((unsigned)vals[5] << 16);
        o.w = (unsigned)vals[6] | ((unsigned)vals[7] << 16);
        *(uint4*)(imgb + (size_t)rest * 1024 + lane * 16) = o;
    } else if (blockIdx.x == 48) {
        int t = threadIdx.x;
        if (t >= 64 && t < 88) {
            int n = t - 64;
            int v = n / 8, rest = n % 8;
            const float* w = (v == 0 ? vr : (v == 1 ? vu : vc)) + rest * 3;
            float phi = w[0], th = w[1], om = w[2];
            float c = cosf(0.5f * th), s = sinf(0.5f * th);
            float ap = -0.5f * (phi + om);
            float am =  0.5f * (phi - om);
            float* o = rotc + n * 4;
            o[0] = cosf(ap) * c;
            o[1] = sinf(ap) * c;
            o[2] = cosf(am) * s;
            o[3] = sinf(am) * s;
        } else if (t >= 96 && t < 104) {
            int h = t - 96;
            float a = sc_b[h];
            for (int cc = 0; cc < 32; ++cc) {
                float s = 0.f;
                for (int f = 0; f < 8; ++f) s += sc_w[h * 256 + f * 32 + cc];
                a = fmaf(ta_b[cc], s, a);
            }
            cgin[h] = a;
        }
    }
}

// ---------------- VQC: 16 lanes hold the 16 complex amplitudes (verified) ----------------
__device__ __forceinline__ float shflg(float v, int grp, int idx) {
    return __shfl(v, grp + idx, 64);
}

__device__ void vqc_run(const float cq[4], const float sq[4],
                        const float* __restrict__ rc,
                        int l, int grp, float exps[4]) {
    float re = (l == 0) ? 1.f : 0.f;
    float im = 0.f;
    #pragma unroll
    for (int layer = 0; layer < 2; ++layer) {
        #pragma unroll
        for (int q = 0; q < 4; ++q) {
            int m = 1 << (3 - q);
            float pre = shflg(re, grp, l ^ m);
            float pim = shflg(im, grp, l ^ m);
            float sg = (l & m) ? sq[q] : -sq[q];
            re = cq[q] * re + sg * pre;
            im = cq[q] * im + sg * pim;
        }
        #pragma unroll
        for (int q = 0; q < 4; ++q) {
            int m = 1 << (3 - q);
            const float* g = rc + (layer * 4 + q) * 4;
            float A = g[0], B = g[1], C = g[2], D = g[3];
            float pre = shflg(re, grp, l ^ m);
            float pim = shflg(im, grp, l ^ m);
            float car, cai, cpr, cpi;
            if (l & m) { car = A; cai = -B; cpr =  C; cpi = -D; }
            else       { car = A; cai =  B; cpr = -C; cpi = -D; }
            float nre = car * re - cai * im + cpr * pre - cpi * pim;
            float nim = car * im + cai * re + cpr * pim + cpi * pre;
            re = nre; im = nim;
        }
        #pragma unroll
        for (int q = 0; q < 4; ++q) {
            int mc = 1 << (3 - q);
            int mt = 1 << (3 - ((q + 1) & 3));
            float pre = shflg(re, grp, l ^ mt);
            float pim = shflg(im, grp, l ^ mt);
            if (l & mc) { re = pre; im = pim; }
        }
    }
    float prob = re * re + im * im;
    float v0 = (l & 8) ? -prob : prob;
    float v1 = (l & 4) ? -prob : prob;
    float v2 = (l & 2) ? -prob : prob;
    float v3 = (l & 1) ? -prob : prob;
    #pragma unroll
    for (int m = 1; m < 16; m <<= 1) {
        v0 += __shfl_xor(v0, m, 64);
        v1 += __shfl_xor(v1, m, 64);
        v2 += __shfl_xor(v2, m, 64);
        v3 += __shfl_xor(v3, m, 64);
    }
    exps[0] = v0; exps[1] = v1; exps[2] = v2; exps[3] = v3;
}

// ---------------- mega-fused: slim regs + 32KB LDS + 3 blocks/CU ----------------
// M=32, 8 waves (wave w = feature f=w). A dbuf 2x16KB; 1-deep x prefetch;
// per-chunk B regs from L2. Epilogue overlays the dbuf (hazard-checked).
__global__ __launch_bounds__(512, 3)
void k_fused(const float* __restrict__ x, const unsigned char* __restrict__ img,
             const float* __restrict__ rotc, const float* __restrict__ cgin,
             const float* __restrict__ h0_b,
             const float* __restrict__ crz_w, const float* __restrict__ crz_b,
             const float* __restrict__ cn_w, const float* __restrict__ cn_b,
             const float* __restrict__ expand_w, const float* __restrict__ expand_b,
             const float* __restrict__ mod_w, const float* __restrict__ mod_b,
             const float* __restrict__ trend_b, const float* __restrict__ seasonal_b,
             const float* __restrict__ fusion_alpha,
             float* __restrict__ out, int Btot)
{
    __shared__ unsigned char lds[32768];           // A dbuf [2][8 f][32 row][64 B]
    float* ghpart = (float*)lds;                   // epi overlay buf0: [8 w][32 row][16] = 16 KB
    float* ghbuf  = (float*)(lds + 16384);         // epi overlay buf1: [32][17] = 2176 B
    float* modt   = (float*)(lds + 16384 + 2304);  // epi overlay buf1: [32][25] = 3200 B

    const int t    = threadIdx.x;
    const int b0   = blockIdx.x * 32;
    const int w    = t >> 6, lane = t & 63, lr = lane & 15, lg = lane >> 4;

    const int arow  = t >> 4;                      // 0..31
    const int spair = t & 15;
    int gr = b0 + arow; if (gr >= Btot) gr = Btot - 1;
    const float* xrow = x + (size_t)gr * KTOT;
    const unsigned char* ib = img + (size_t)(w * 24) * 1024 + (size_t)lane * 16;

    // x prologue (chunk 0)
    float4 ra[4];
    #pragma unroll
    for (int u = 0; u < 4; ++u) ra[u] = *(const float4*)&xrow[spair * 16 + u * 4];

    f32x4 acc[3][2], accg[2];
    #pragma unroll
    for (int cf = 0; cf < 3; ++cf) {
        acc[cf][0] = (f32x4){0.f, 0.f, 0.f, 0.f};
        acc[cf][1] = (f32x4){0.f, 0.f, 0.f, 0.f};
    }
    accg[0] = (f32x4){0.f, 0.f, 0.f, 0.f};
    accg[1] = (f32x4){0.f, 0.f, 0.f, 0.f};

    const int wb   = (arow * 64 + spair * 4) ^ ((arow & 7) << 4);
    const int ar0  = (lr * 64 + lg * 16) ^ ((lr & 7) << 4);
    const int ar1  = ((lr + 16) * 64 + lg * 16) ^ ((lr & 7) << 4);

    #pragma unroll
    for (int kc = 0; kc < NSCH; ++kc) {
        const int bufo = (kc & 1) * 16384;
        // publish A(kc) from ra
        {
            const float* rf = (const float*)ra;
            #pragma unroll
            for (int f = 0; f < 8; ++f)
                *(unsigned*)&lds[bufo + f * 2048 + wb] = pack2(rf[f], rf[8 + f]);
        }
        // x prefetch (kc+1), 1-deep
        if (kc + 1 < NSCH) {
            int off = (kc + 1) * 256 + spair * 16;
            if (off > KTOT - 16) off = KTOT - 16;  // pad s>=168: zero-B cols
            #pragma unroll
            for (int u = 0; u < 4; ++u) ra[u] = *(const float4*)&xrow[off + u * 4];
        }
        // B(kc): per-chunk, lane-exact, L2-resident
        bf16x8 Br[4];
        #pragma unroll
        for (int cf = 0; cf < 4; ++cf) Br[cf] = *(const bf16x8*)&ib[(cf * 6 + kc) * 1024];
        __syncthreads();
        {
            bf16x8 a0 = *(const bf16x8*)&lds[bufo + w * 2048 + ar0];
            bf16x8 a1 = *(const bf16x8*)&lds[bufo + w * 2048 + ar1];
            #pragma unroll
            for (int cf = 0; cf < 3; ++cf) {
                acc[cf][0] = __builtin_amdgcn_mfma_f32_16x16x32_bf16(a0, Br[cf], acc[cf][0], 0, 0, 0);
                acc[cf][1] = __builtin_amdgcn_mfma_f32_16x16x32_bf16(a1, Br[cf], acc[cf][1], 0, 0, 0);
            }
            accg[0] = __builtin_amdgcn_mfma_f32_16x16x32_bf16(a0, Br[3], accg[0], 0, 0, 0);
            accg[1] = __builtin_amdgcn_mfma_f32_16x16x32_bf16(a1, Br[3], accg[1], 0, 0, 0);
        }
    }

    // ---- epi 1: gh partials into buf0 overlay (buf0 dead since kc=5 barrier) ----
    #pragma unroll
    for (int mf = 0; mf < 2; ++mf)
        #pragma unroll
        for (int reg = 0; reg < 4; ++reg)
            ghpart[(w * 32 + mf * 16 + lg * 4 + reg) * 16 + lr] = accg[mf][reg];
    __syncthreads();
    {
        int row = t >> 4, col = t & 15;            // 512 = 32x16 exactly
        float s = 0.f;
        #pragma unroll
        for (int f = 0; f < 8; ++f) s += ghpart[f * 512 + row * 16 + col];
        ghbuf[row * 17 + col] = s;                 // buf1 overlay (A-reads done pre-barrier)
    }
    __syncthreads();

    // ---- epi 2: VQC chain, single pass 32 rows (verified r6/r7) ----
    {
        const int rl  = t >> 4;
        const int l   = t & 15;
        const int grp = lane & 48;
        float gin[HID], h0v[HID];
        #pragma unroll
        for (int h = 0; h < HID; ++h) {
            gin[h] = ftanh(ghbuf[rl * 17 + h]     + cgin[h]);
            h0v[h] = ftanh(ghbuf[rl * 17 + 8 + h] + h0_b[h]);
        }
        float rz[4];
        #pragma unroll
        for (int q = 0; q < 4; ++q) {
            float a = crz_b[q];
            #pragma unroll
            for (int k = 0; k < 8; ++k) a = fmaf(gin[k], crz_w[q * 16 + k], a);
            #pragma unroll
            for (int k = 0; k < 8; ++k) a = fmaf(h0v[k], crz_w[q * 16 + 8 + k], a);
            rz[q] = ftanh(a) * PI_F;
        }
        float cq[4], sq[4];
        #pragma unroll
        for (int q = 0; q < 4; ++q) { cq[q] = __cosf(0.5f * rz[q]); sq[q] = __sinf(0.5f * rz[q]); }

        float er[4], ez[4];
        vqc_run(cq, sq, rotc + 0 * 32, l, grp, er);
        vqc_run(cq, sq, rotc + 1 * 32, l, grp, ez);

        float rr[HID], zz[HID];
        #pragma unroll
        for (int h = 0; h < HID; ++h) {
            float a = expand_b[h], b = expand_b[h];
            #pragma unroll
            for (int q = 0; q < 4; ++q) {
                a = fmaf(er[q], expand_w[h * 4 + q], a);
                b = fmaf(ez[q], expand_w[h * 4 + q], b);
            }
            rr[h] = sigm(a);
            zz[h] = sigm(b);
        }
        float ni[4];
        #pragma unroll
        for (int q = 0; q < 4; ++q) {
            float a = cn_b[q];
            #pragma unroll
            for (int k = 0; k < 8; ++k) a = fmaf(rr[k] * h0v[k], cn_w[q * 16 + k], a);
            #pragma unroll
            for (int k = 0; k < 8; ++k) a = fmaf(gin[k], cn_w[q * 16 + 8 + k], a);
            ni[q] = ftanh(a) * PI_F;
        }
        #pragma unroll
        for (int q = 0; q < 4; ++q) { cq[q] = __cosf(0.5f * ni[q]); sq[q] = __sinf(0.5f * ni[q]); }
        float en[4];
        vqc_run(cq, sq, rotc + 2 * 32, l, grp, en);

        float hn[HID];
        #pragma unroll
        for (int h = 0; h < HID; ++h) {
            float a = expand_b[h];
            #pragma unroll
            for (int q = 0; q < 4; ++q) a = fmaf(en[q], expand_w[h * 4 + q], a);
            float nn = ftanh(a);
            hn[h] = (1.f - zz[h]) * nn + zz[h] * h0v[h];
        }
        int pp = l;
        float a = mod_b[pp];
        #pragma unroll
        for (int h = 0; h < HID; ++h) a = fmaf(hn[h], mod_w[pp * 8 + h], a);
        modt[rl * 25 + pp] = ftanh(a);
        if (l < 8) {
            pp = l + 16;
            a = mod_b[pp];
            #pragma unroll
            for (int h = 0; h < HID; ++h) a = fmaf(hn[h], mod_w[pp * 8 + h], a);
            modt[rl * 25 + pp] = ftanh(a);
        }
    }
    __syncthreads();

    // ---- epi 3: fuse interleaved T/S pairs, store (verified r7/r8) ----
    const float alpha = sigm(fusion_alpha[0]);
    #pragma unroll
    for (int cf = 0; cf < 3; ++cf) {
        int p = cf * 8 + (lr >> 1);
        float tb = trend_b[p], sb = seasonal_b[p];
        #pragma unroll
        for (int mf = 0; mf < 2; ++mf) {
            #pragma unroll
            for (int reg = 0; reg < 4; ++reg) {
                int rl = mf * 16 + lg * 4 + reg;
                float v  = acc[cf][mf][reg];
                float pt = __shfl_xor(v, 1, 64);
                if (!(lr & 1)) {                   // even lane: T; partner: S
                    int R = b0 + rl;
                    if (R < Btot) {
                        float md = modt[rl * 25 + p];
                        float res = alpha * ((pt + sb) * (1.f + md))
                                  + (1.f - alpha) * (v + tb);
                        out[(size_t)R * 192 + p * 8 + w] = res;
                    }
                }
            }
        }
    }
}

extern "C" void kernel_launch(void* const* d_in, const int* in_sizes, int n_in,
                              void* d_out, int out_size, void* d_ws, size_t ws_size,
                              hipStream_t stream) {
    const float* x          = (const float*)d_in[0];
    const float* decomp_w   = (const float*)d_in[1];
    const float* trend_w    = (const float*)d_in[2];
    const float* trend_b    = (const float*)d_in[3];
    const float* seasonal_w = (const float*)d_in[4];
    const float* seasonal_b = (const float*)d_in[5];
    const float* h0_w       = (const float*)d_in[6];
    const float* h0_b       = (const float*)d_in[7];
    const float* ta_w       = (const float*)d_in[8];
    const float* ta_b       = (const float*)d_in[9];
    const float* sc_w       = (const float*)d_in[10];
    const float* sc_b       = (const float*)d_in[11];
    const float* crz_w      = (const float*)d_in[12];
    const float* crz_b      = (const float*)d_in[13];
    const float* cn_w       = (const float*)d_in[14];
    const float* cn_b       = (const float*)d_in[15];
    const float* vqc_r      = (const float*)d_in[16];
    const float* vqc_u      = (const float*)d_in[17];
    const float* vqc_c      = (const float*)d_in[18];
    const float* expand_w   = (const float*)d_in[19];
    const float* expand_b   = (const float*)d_in[20];
    const float* mod_w      = (const float*)d_in[21];
    const float* mod_b      = (const float*)d_in[22];
    const float* fus_a      = (const float*)d_in[23];
    float* out = (float*)d_out;

    float* ws   = (float*)d_ws;
    float* rotc = ws + WS_ROTC;
    float* cgin = ws + WS_CGIN;
    float* Wt   = ws + WS_WT;
    unsigned char* img = (unsigned char*)d_ws + WS_IMG_BYTE;

    const int Btot = in_sizes[0] / (SEQ * NF);

    k_compose<<<(SEQ * 640 + 255) / 256, 256, 0, stream>>>(decomp_w, trend_w, seasonal_w, ta_w, Wt);
    k_img<<<49, 256, 0, stream>>>(Wt, sc_w, h0_w, vqc_r, vqc_u, vqc_c, sc_b, ta_b,
                                  rotc, cgin, img);

    k_fused<<<(Btot + 31) / 32, 512, 0, stream>>>(x, img, rotc, cgin, h0_b,
                                                  crz_w, crz_b, cn_w, cn_b,
                                                  expand_w, expand_b, mod_w, mod_b,
                                                  trend_b, seasonal_b, fus_a, out, Btot);
}